// Round 5
// baseline (390.761 us; speedup 1.0000x reference)
//
#include <hip/hip_runtime.h>
#include <hip/hip_bf16.h>

#define NB 32
#define NS 2048
#define NDD 1024
#define NDE 1024
#define NDA 1024
#define NEGV (-1000000000.0f)

typedef __attribute__((ext_vector_type(8))) __bf16 bf16x8;
typedef __attribute__((ext_vector_type(4))) float f32x4;

__device__ __forceinline__ float fast_tanh(float x) {
    x = fminf(10.0f, fmaxf(-10.0f, x));
    float e = __expf(2.0f * x);
    return __fdividef(e - 1.0f, e + 1.0f);
}

// ---------------- We (f32) -> bf16 ----------------
__global__ void prep_we(const float* __restrict__ Wc, __bf16* __restrict__ We) {
    int f = blockIdx.x * 256 + threadIdx.x;
    int a  = f >> 8;
    int k4 = f & 255;
    float4 v = *reinterpret_cast<const float4*>(Wc + (size_t)a * (NDD + NDE) + NDD + k4 * 4);
    union { __bf16 h[4]; uint2 u; } pk;
    pk.h[0] = (__bf16)v.x; pk.h[1] = (__bf16)v.y;
    pk.h[2] = (__bf16)v.z; pk.h[3] = (__bf16)v.w;
    *reinterpret_cast<uint2*>(We + (size_t)a * NDE + k4 * 4) = pk.u;
}

// ---------------- E (f32) -> bf16, 8 elems/thread ----------------
__global__ void prep_e(const float* __restrict__ E, __bf16* __restrict__ Eb) {
    size_t i = ((size_t)blockIdx.x * 256 + threadIdx.x) * 8;
    float4 x = *reinterpret_cast<const float4*>(E + i);
    float4 y = *reinterpret_cast<const float4*>(E + i + 4);
    union { __bf16 h[8]; uint4 u; } pk;
    pk.h[0] = (__bf16)x.x; pk.h[1] = (__bf16)x.y; pk.h[2] = (__bf16)x.z; pk.h[3] = (__bf16)x.w;
    pk.h[4] = (__bf16)y.x; pk.h[5] = (__bf16)y.y; pk.h[6] = (__bf16)y.z; pk.h[7] = (__bf16)y.w;
    *reinterpret_cast<uint4*>(Eb + i) = pk.u;
}

// ---------------- q_proj = query @ Wq^T (f32, exact) ----------------
__global__ void qproj_kernel(const float* __restrict__ q, const float* __restrict__ Wc,
                             float* __restrict__ qp) {
    __shared__ float qs[NDD];
    int b = blockIdx.y;
    int a = blockIdx.x * 256 + threadIdx.x;
    float4 qv = *reinterpret_cast<const float4*>(q + (size_t)b * NDD + threadIdx.x * 4);
    *reinterpret_cast<float4*>(qs + threadIdx.x * 4) = qv;
    __syncthreads();
    const float* wrow = Wc + (size_t)a * (NDD + NDE);
    float acc = 0.f;
#pragma unroll 4
    for (int k4 = 0; k4 < 256; ++k4) {
        float4 w = *reinterpret_cast<const float4*>(wrow + k4 * 4);
        acc += qs[k4*4+0] * w.x + qs[k4*4+1] * w.y + qs[k4*4+2] * w.z + qs[k4*4+3] * w.w;
    }
    qp[(size_t)b * NDA + a] = acc;
}

// ---------------- pure-bf16 m97 replica: fused GEMM + tanh + V-dot ----------------
// 128x128 tile, BK=32, 256 thr / 4 waves (2x2), double-buffered bf16 LDS tiles,
// BOTH operands staged via global_load_lds w16 with involution slot swizzle
// (slot ^= (r>>1)&3): linear LDS dest + inverse-swizzled source + swizzled read.
__global__ __launch_bounds__(256) void score_kernel_bf16(
    const __bf16* __restrict__ Eb, const __bf16* __restrict__ We,
    const float* __restrict__ qp, const float* __restrict__ Vv,
    float* __restrict__ scores_p) {
    __shared__ __align__(16) __bf16 As[2][128 * 32];   // 8 KB each
    __shared__ __align__(16) __bf16 Bs[2][128 * 32];
    __shared__ float ps_lds[128][2];

    const int tid    = threadIdx.x;
    const int lane   = tid & 63;
    const int lane15 = lane & 15;
    const int h      = lane >> 4;
    const int wid    = tid >> 6;
    const int wr     = wid >> 1;
    const int wc     = wid & 1;

    const int bid = blockIdx.x;
    const int xcd = bid & 7;
    const int j   = bid >> 3;
    const int m   = xcd * 64 + (j >> 3);
    const int n   = j & 7;
    const int row0  = m * 128;
    const int ncol0 = n * 128;
    const int b     = m >> 4;

    f32x4 acc[4][4];
#pragma unroll
    for (int mi = 0; mi < 4; ++mi)
#pragma unroll
        for (int ni = 0; ni < 4; ++ni)
            acc[mi][ni] = (f32x4){0.f, 0.f, 0.f, 0.f};

    const int wbyte = wid * 1024;

#define STG(SRC, base_row, LDSBUF, kc)                                                 \
    {                                                                                  \
        _Pragma("unroll")                                                              \
        for (int i = 0; i < 2; ++i) {                                                  \
            int ib = i * 4096 + tid * 16;                                              \
            int r  = ib >> 6;                                                          \
            int sl = (ib >> 4) & 3;                                                    \
            int sg = sl ^ ((r >> 1) & 3);                                              \
            const __bf16* g = SRC + (size_t)((base_row) + r) * 1024 + (kc) + sg * 8;   \
            __builtin_amdgcn_global_load_lds(                                          \
                (const __attribute__((address_space(1))) unsigned*)g,                  \
                (__attribute__((address_space(3))) unsigned*)((char*)LDSBUF + i * 4096 + wbyte), \
                16, 0, 0);                                                             \
        }                                                                              \
    }

    STG(Eb, row0, &As[0][0], 0)
    STG(We, ncol0, &Bs[0][0], 0)
    __syncthreads();

    for (int it = 0; it < 32; ++it) {
        const int cur = it & 1;
        if (it < 31) {
            STG(Eb, row0, &As[cur ^ 1][0], (it + 1) * 32)
            STG(We, ncol0, &Bs[cur ^ 1][0], (it + 1) * 32)
        }
        const char* Ab = (const char*)&As[cur][0];
        const char* Bb = (const char*)&Bs[cur][0];
        bf16x8 bfr[4], afr[4];
#pragma unroll
        for (int ni = 0; ni < 4; ++ni) {
            int cr = wc * 64 + ni * 16 + lane15;
            bfr[ni] = *reinterpret_cast<const bf16x8*>(Bb + cr * 64 + ((h ^ ((cr >> 1) & 3)) * 16));
        }
#pragma unroll
        for (int mi = 0; mi < 4; ++mi) {
            int r = wr * 64 + mi * 16 + lane15;
            afr[mi] = *reinterpret_cast<const bf16x8*>(Ab + r * 64 + ((h ^ ((r >> 1) & 3)) * 16));
        }
#pragma unroll
        for (int mi = 0; mi < 4; ++mi)
#pragma unroll
            for (int ni = 0; ni < 4; ++ni)
                acc[mi][ni] = __builtin_amdgcn_mfma_f32_16x16x32_bf16(afr[mi], bfr[ni], acc[mi][ni], 0, 0, 0);
        __syncthreads();
    }

    float qv[4], vv[4];
#pragma unroll
    for (int ni = 0; ni < 4; ++ni) {
        int col = ncol0 + wc * 64 + ni * 16 + lane15;
        qv[ni] = qp[(size_t)b * NDA + col];
        vv[ni] = Vv[col];
    }
#pragma unroll
    for (int mi = 0; mi < 4; ++mi)
#pragma unroll
        for (int jj = 0; jj < 4; ++jj) {
            float s = 0.f;
#pragma unroll
            for (int ni = 0; ni < 4; ++ni)
                s += fast_tanh(qv[ni] + acc[mi][ni][jj]) * vv[ni];
            s += __shfl_xor(s, 1);
            s += __shfl_xor(s, 2);
            s += __shfl_xor(s, 4);
            s += __shfl_xor(s, 8);
            if (lane15 == 0)
                ps_lds[wr * 64 + mi * 16 + h * 4 + jj][wc] = s;
        }
    __syncthreads();
    if (tid < 128)
        scores_p[(size_t)n * (NB * NS) + row0 + tid] = ps_lds[tid][0] + ps_lds[tid][1];
}

// ---------------- fallback (R4): f32 A reg-staged ----------------
__global__ __launch_bounds__(256, 4) void score_kernel_f32(
    const float* __restrict__ E, const __bf16* __restrict__ We,
    const float* __restrict__ qp, const float* __restrict__ Vv,
    float* __restrict__ scores_p) {
    __shared__ __align__(16) __bf16 As[2][128 * 32];
    __shared__ __align__(16) __bf16 Bs[2][128 * 32];
    __shared__ float ps_lds[128][2];

    const int tid    = threadIdx.x;
    const int lane   = tid & 63;
    const int lane15 = lane & 15;
    const int h      = lane >> 4;
    const int wid    = tid >> 6;
    const int wr     = wid >> 1;
    const int wc     = wid & 1;

    const int bid = blockIdx.x;
    const int xcd = bid & 7;
    const int j   = bid >> 3;
    const int m   = xcd * 64 + (j >> 3);
    const int n   = j & 7;
    const int row0  = m * 128;
    const int ncol0 = n * 128;
    const int b     = m >> 4;

    f32x4 acc[4][4];
#pragma unroll
    for (int mi = 0; mi < 4; ++mi)
#pragma unroll
        for (int ni = 0; ni < 4; ++ni)
            acc[mi][ni] = (f32x4){0.f, 0.f, 0.f, 0.f};

    const int wbyte = wid * 1024;
    float4 st[4];

#define A_LOAD(kc)                                                                     \
    {                                                                                  \
        _Pragma("unroll")                                                              \
        for (int i = 0; i < 4; ++i)                                                    \
            st[i] = *reinterpret_cast<const float4*>(                                  \
                E + (size_t)(row0 + i * 32 + (tid >> 3)) * NDE + (kc) + (tid & 7) * 4);\
    }

#define A_WRITE(buf)                                                                   \
    {                                                                                  \
        _Pragma("unroll")                                                              \
        for (int i = 0; i < 4; ++i) {                                                  \
            int r  = i * 32 + (tid >> 3);                                              \
            int sl = ((tid & 7) >> 1) ^ ((r >> 1) & 3);                                \
            union { __bf16 hh[4]; uint2 u; } pk;                                       \
            pk.hh[0] = (__bf16)st[i].x; pk.hh[1] = (__bf16)st[i].y;                    \
            pk.hh[2] = (__bf16)st[i].z; pk.hh[3] = (__bf16)st[i].w;                    \
            *reinterpret_cast<uint2*>((char*)&As[buf][0] + r * 64 + sl * 16 + (tid & 1) * 8) = pk.u; \
        }                                                                              \
    }

#define B_STAGE(buf, kc)                                                               \
    {                                                                                  \
        _Pragma("unroll")                                                              \
        for (int i = 0; i < 2; ++i) {                                                  \
            int ib = i * 4096 + tid * 16;                                              \
            int r  = ib >> 6;                                                          \
            int sl = (ib >> 4) & 3;                                                    \
            int sg = sl ^ ((r >> 1) & 3);                                              \
            const __bf16* g = We + (size_t)(ncol0 + r) * NDE + (kc) + sg * 8;          \
            __builtin_amdgcn_global_load_lds(                                          \
                (const __attribute__((address_space(1))) unsigned*)g,                  \
                (__attribute__((address_space(3))) unsigned*)((char*)&Bs[buf][0] + i * 4096 + wbyte), \
                16, 0, 0);                                                             \
        }                                                                              \
    }

    A_LOAD(0)
    B_STAGE(0, 0)
    A_WRITE(0)
    __syncthreads();

    for (int it = 0; it < 32; ++it) {
        const int cur = it & 1;
        if (it < 31) {
            A_LOAD((it + 1) * 32)
            B_STAGE(cur ^ 1, (it + 1) * 32)
        }
        const char* Ab = (const char*)&As[cur][0];
        const char* Bb = (const char*)&Bs[cur][0];
        bf16x8 bfr[4], afr[4];
#pragma unroll
        for (int ni = 0; ni < 4; ++ni) {
            int cr = wc * 64 + ni * 16 + lane15;
            bfr[ni] = *reinterpret_cast<const bf16x8*>(Bb + cr * 64 + ((h ^ ((cr >> 1) & 3)) * 16));
        }
#pragma unroll
        for (int mi = 0; mi < 4; ++mi) {
            int r = wr * 64 + mi * 16 + lane15;
            afr[mi] = *reinterpret_cast<const bf16x8*>(Ab + r * 64 + ((h ^ ((r >> 1) & 3)) * 16));
        }
#pragma unroll
        for (int mi = 0; mi < 4; ++mi)
#pragma unroll
            for (int ni = 0; ni < 4; ++ni)
                acc[mi][ni] = __builtin_amdgcn_mfma_f32_16x16x32_bf16(afr[mi], bfr[ni], acc[mi][ni], 0, 0, 0);
        if (it < 31) A_WRITE(cur ^ 1)
        __syncthreads();
    }

    float qv[4], vv[4];
#pragma unroll
    for (int ni = 0; ni < 4; ++ni) {
        int col = ncol0 + wc * 64 + ni * 16 + lane15;
        qv[ni] = qp[(size_t)b * NDA + col];
        vv[ni] = Vv[col];
    }
#pragma unroll
    for (int mi = 0; mi < 4; ++mi)
#pragma unroll
        for (int jj = 0; jj < 4; ++jj) {
            float s = 0.f;
#pragma unroll
            for (int ni = 0; ni < 4; ++ni)
                s += fast_tanh(qv[ni] + acc[mi][ni][jj]) * vv[ni];
            s += __shfl_xor(s, 1);
            s += __shfl_xor(s, 2);
            s += __shfl_xor(s, 4);
            s += __shfl_xor(s, 8);
            if (lane15 == 0)
                ps_lds[wr * 64 + mi * 16 + h * 4 + jj][wc] = s;
        }
    __syncthreads();
    if (tid < 128)
        scores_p[(size_t)n * (NB * NS) + row0 + tid] = ps_lds[tid][0] + ps_lds[tid][1];
}

// ---------------- masked softmax over s (sums 8 partials), per b ----------------
__global__ void softmax_kernel(const float* __restrict__ sp, const int* __restrict__ mask,
                               float* __restrict__ wout) {
    int b = blockIdx.x;
    const int* mrow = mask + (size_t)b * NS;
    float v[8];
    float lmax = -INFINITY;
#pragma unroll
    for (int jj = 0; jj < 8; ++jj) {
        int s = threadIdx.x + 256 * jj;
        float sc = 0.f;
#pragma unroll
        for (int nn = 0; nn < 8; ++nn) sc += sp[(size_t)nn * (NB * NS) + b * NS + s];
        v[jj] = (mrow[s] == 0) ? NEGV : sc;
        lmax = fmaxf(lmax, v[jj]);
    }
#pragma unroll
    for (int mm = 1; mm <= 32; mm <<= 1) lmax = fmaxf(lmax, __shfl_xor(lmax, mm));
    __shared__ float redm[4], reds[4];
    if ((threadIdx.x & 63) == 0) redm[threadIdx.x >> 6] = lmax;
    __syncthreads();
    float bmax = fmaxf(fmaxf(redm[0], redm[1]), fmaxf(redm[2], redm[3]));
    float lsum = 0.f;
#pragma unroll
    for (int jj = 0; jj < 8; ++jj) { v[jj] = __expf(v[jj] - bmax); lsum += v[jj]; }
#pragma unroll
    for (int mm = 1; mm <= 32; mm <<= 1) lsum += __shfl_xor(lsum, mm);
    if ((threadIdx.x & 63) == 0) reds[threadIdx.x >> 6] = lsum;
    __syncthreads();
    float inv = __fdividef(1.0f, reds[0] + reds[1] + reds[2] + reds[3]);
#pragma unroll
    for (int jj = 0; jj < 8; ++jj) wout[(size_t)b * NS + threadIdx.x + 256 * jj] = v[jj] * inv;
}

// ---------------- context = w @ E (f32 E for accuracy) ----------------
__global__ void context_kernel(const float* __restrict__ E, const float* __restrict__ w,
                               float* __restrict__ ctx) {
    int b  = blockIdx.x >> 3;
    int dc = blockIdx.x & 7;
    int d2 = dc * 64 + (threadIdx.x & 63);
    int s0 = (threadIdx.x >> 6) * 512;
    const float2* Eb = reinterpret_cast<const float2*>(E) + (size_t)b * NS * (NDE / 2);
    const float* wb = w + (size_t)b * NS;
    float ax = 0.f, ay = 0.f;
#pragma unroll 8
    for (int s = s0; s < s0 + 512; ++s) {
        float ws = wb[s];
        float2 e = Eb[(size_t)s * (NDE / 2) + d2];
        ax = fmaf(ws, e.x, ax);
        ay = fmaf(ws, e.y, ay);
    }
    __shared__ float2 part[256];
    part[threadIdx.x] = make_float2(ax, ay);
    __syncthreads();
    if (threadIdx.x < 64) {
        float2 p0 = part[threadIdx.x], p1 = part[threadIdx.x + 64];
        float2 p2 = part[threadIdx.x + 128], p3 = part[threadIdx.x + 192];
        float2 r = make_float2(p0.x + p1.x + p2.x + p3.x, p0.y + p1.y + p2.y + p3.y);
        reinterpret_cast<float2*>(ctx + (size_t)b * NDD + dc * 128)[threadIdx.x] = r;
    }
}

extern "C" void kernel_launch(void* const* d_in, const int* in_sizes, int n_in,
                              void* d_out, int out_size, void* d_ws, size_t ws_size,
                              hipStream_t stream) {
    const float* query = (const float*)d_in[0];
    const float* enc   = (const float*)d_in[1];
    const int*   mask  = (const int*)d_in[2];
    const float* Wc    = (const float*)d_in[3];
    const float* V     = (const float*)d_in[4];

    float* out = (float*)d_out;
    float* ctx = out;                       // (32,1024)
    float* wts = out + NB * NDD;            // (32,2048)

    const size_t WE_B = (size_t)NDA * NDE * 2;        // 2 MB
    const size_t QP_B = (size_t)NB * NDA * 4;         // 128 KB
    const size_t SP_B = (size_t)8 * NB * NS * 4;      // 2 MB
    const size_t EB_B = (size_t)NB * NS * NDE * 2;    // 134.2 MB

    char* ws = (char*)d_ws;
    __bf16* We = (__bf16*)ws;
    float*  qp = (float*)(ws + WE_B);
    float*  sp = (float*)(ws + WE_B + QP_B);
    __bf16* Eb = (__bf16*)(ws + WE_B + QP_B + SP_B);

    hipLaunchKernelGGL(prep_we,      dim3(1024),  dim3(256), 0, stream, Wc, We);
    hipLaunchKernelGGL(qproj_kernel, dim3(4, NB), dim3(256), 0, stream, query, Wc, qp);

    if (ws_size >= WE_B + QP_B + SP_B + EB_B) {
        hipLaunchKernelGGL(prep_e,           dim3(32768), dim3(256), 0, stream, enc, Eb);
        hipLaunchKernelGGL(score_kernel_bf16,dim3(4096),  dim3(256), 0, stream, Eb, We, qp, V, sp);
    } else {
        hipLaunchKernelGGL(score_kernel_f32, dim3(4096),  dim3(256), 0, stream, enc, We, qp, V, sp);
    }
    hipLaunchKernelGGL(softmax_kernel, dim3(NB),  dim3(256), 0, stream, sp, mask, wts);
    hipLaunchKernelGGL(context_kernel, dim3(256), dim3(256), 0, stream, enc, wts, ctx);
}

// Round 7
// 315.923 us; speedup vs baseline: 1.2369x; 1.2369x over previous
//
#include <hip/hip_runtime.h>
#include <hip/hip_bf16.h>

#define NB 32
#define NS 2048
#define NDD 1024
#define NDE 1024
#define NDA 1024
#define NEGV (-1000000000.0f)

typedef __attribute__((ext_vector_type(8))) __bf16 bf16x8;
typedef __attribute__((ext_vector_type(4))) float f32x4;

__device__ __forceinline__ float fast_tanh(float x) {
    x = fminf(10.0f, fmaxf(-10.0f, x));
    float e = __expf(2.0f * x);
    return __fdividef(e - 1.0f, e + 1.0f);
}

__device__ __forceinline__ float bfu2f(unsigned short v) {
    union { unsigned u; float f; } c; c.u = (unsigned)v << 16; return c.f;
}

// ---------------- We (f32) -> bf16 ----------------
__global__ void prep_we(const float* __restrict__ Wc, __bf16* __restrict__ We) {
    int f = blockIdx.x * 256 + threadIdx.x;
    int a  = f >> 8;
    int k4 = f & 255;
    float4 v = *reinterpret_cast<const float4*>(Wc + (size_t)a * (NDD + NDE) + NDD + k4 * 4);
    union { __bf16 h[4]; uint2 u; } pk;
    pk.h[0] = (__bf16)v.x; pk.h[1] = (__bf16)v.y;
    pk.h[2] = (__bf16)v.z; pk.h[3] = (__bf16)v.w;
    *reinterpret_cast<uint2*>(We + (size_t)a * NDE + k4 * 4) = pk.u;
}

// ---------------- E (f32) -> bf16, nontemporal E reads (don't evict Eb from L3) ----------------
__global__ void prep_e(const float* __restrict__ E, __bf16* __restrict__ Eb) {
    size_t i = ((size_t)blockIdx.x * 256 + threadIdx.x) * 8;
    f32x4 x = __builtin_nontemporal_load(reinterpret_cast<const f32x4*>(E + i));
    f32x4 y = __builtin_nontemporal_load(reinterpret_cast<const f32x4*>(E + i + 4));
    union { __bf16 h[8]; uint4 u; } pk;
    pk.h[0] = (__bf16)x[0]; pk.h[1] = (__bf16)x[1]; pk.h[2] = (__bf16)x[2]; pk.h[3] = (__bf16)x[3];
    pk.h[4] = (__bf16)y[0]; pk.h[5] = (__bf16)y[1]; pk.h[6] = (__bf16)y[2]; pk.h[7] = (__bf16)y[3];
    *reinterpret_cast<uint4*>(Eb + i) = pk.u;
}

// ---------------- q_proj = query @ Wq^T (f32, exact) ----------------
__global__ void qproj_kernel(const float* __restrict__ q, const float* __restrict__ Wc,
                             float* __restrict__ qp) {
    __shared__ float qs[NDD];
    int b = blockIdx.y;
    int a = blockIdx.x * 256 + threadIdx.x;
    float4 qv = *reinterpret_cast<const float4*>(q + (size_t)b * NDD + threadIdx.x * 4);
    *reinterpret_cast<float4*>(qs + threadIdx.x * 4) = qv;
    __syncthreads();
    const float* wrow = Wc + (size_t)a * (NDD + NDE);
    float acc = 0.f;
#pragma unroll 4
    for (int k4 = 0; k4 < 256; ++k4) {
        float4 w = *reinterpret_cast<const float4*>(wrow + k4 * 4);
        acc += qs[k4*4+0] * w.x + qs[k4*4+1] * w.y + qs[k4*4+2] * w.z + qs[k4*4+3] * w.w;
    }
    qp[(size_t)b * NDA + a] = acc;
}

// ---------------- pure-bf16 m97 replica: fused GEMM + tanh + V-dot ----------------
// 128x128 tile, BK=32, 256 thr / 4 waves (2x2), double-buffered bf16 LDS tiles,
// both operands via global_load_lds w16, involution slot swizzle (slot ^= (r>>1)&3).
// Epilogue partials reuse As[0] (LDS exactly 32 KB -> 5 blocks/CU).
__global__ __launch_bounds__(256) void score_kernel_bf16(
    const __bf16* __restrict__ Eb, const __bf16* __restrict__ We,
    const float* __restrict__ qp, const float* __restrict__ Vv,
    float* __restrict__ scores_p) {
    __shared__ __align__(16) __bf16 As[2][128 * 32];   // 8 KB each
    __shared__ __align__(16) __bf16 Bs[2][128 * 32];

    const int tid    = threadIdx.x;
    const int lane   = tid & 63;
    const int lane15 = lane & 15;
    const int h      = lane >> 4;
    const int wid    = tid >> 6;
    const int wr     = wid >> 1;
    const int wc     = wid & 1;

    const int bid = blockIdx.x;
    const int xcd = bid & 7;
    const int j   = bid >> 3;
    const int m   = xcd * 64 + (j >> 3);
    const int n   = j & 7;
    const int row0  = m * 128;
    const int ncol0 = n * 128;
    const int b     = m >> 4;

    f32x4 acc[4][4];
#pragma unroll
    for (int mi = 0; mi < 4; ++mi)
#pragma unroll
        for (int ni = 0; ni < 4; ++ni)
            acc[mi][ni] = (f32x4){0.f, 0.f, 0.f, 0.f};

    const int wbyte = wid * 1024;

#define STG(SRC, base_row, LDSBUF, kc)                                                 \
    {                                                                                  \
        _Pragma("unroll")                                                              \
        for (int i = 0; i < 2; ++i) {                                                  \
            int ib = i * 4096 + tid * 16;                                              \
            int r  = ib >> 6;                                                          \
            int sl = (ib >> 4) & 3;                                                    \
            int sg = sl ^ ((r >> 1) & 3);                                              \
            const __bf16* g = SRC + (size_t)((base_row) + r) * 1024 + (kc) + sg * 8;   \
            __builtin_amdgcn_global_load_lds(                                          \
                (const __attribute__((address_space(1))) unsigned*)g,                  \
                (__attribute__((address_space(3))) unsigned*)((char*)LDSBUF + i * 4096 + wbyte), \
                16, 0, 0);                                                             \
        }                                                                              \
    }

    STG(Eb, row0, &As[0][0], 0)
    STG(We, ncol0, &Bs[0][0], 0)
    __syncthreads();

    for (int it = 0; it < 32; ++it) {
        const int cur = it & 1;
        if (it < 31) {
            STG(Eb, row0, &As[cur ^ 1][0], (it + 1) * 32)
            STG(We, ncol0, &Bs[cur ^ 1][0], (it + 1) * 32)
        }
        const char* Ab = (const char*)&As[cur][0];
        const char* Bb = (const char*)&Bs[cur][0];
        bf16x8 bfr[4], afr[4];
#pragma unroll
        for (int ni = 0; ni < 4; ++ni) {
            int cr = wc * 64 + ni * 16 + lane15;
            bfr[ni] = *reinterpret_cast<const bf16x8*>(Bb + cr * 64 + ((h ^ ((cr >> 1) & 3)) * 16));
        }
#pragma unroll
        for (int mi = 0; mi < 4; ++mi) {
            int r = wr * 64 + mi * 16 + lane15;
            afr[mi] = *reinterpret_cast<const bf16x8*>(Ab + r * 64 + ((h ^ ((r >> 1) & 3)) * 16));
        }
#pragma unroll
        for (int mi = 0; mi < 4; ++mi)
#pragma unroll
            for (int ni = 0; ni < 4; ++ni)
                acc[mi][ni] = __builtin_amdgcn_mfma_f32_16x16x32_bf16(afr[mi], bfr[ni], acc[mi][ni], 0, 0, 0);
        __syncthreads();
    }

    float qv[4], vv[4];
#pragma unroll
    for (int ni = 0; ni < 4; ++ni) {
        int col = ncol0 + wc * 64 + ni * 16 + lane15;
        qv[ni] = qp[(size_t)b * NDA + col];
        vv[ni] = Vv[col];
    }
    float* ps = reinterpret_cast<float*>(&As[0][0]);   // As retired; reuse as [128][2] f32
#pragma unroll
    for (int mi = 0; mi < 4; ++mi)
#pragma unroll
        for (int jj = 0; jj < 4; ++jj) {
            float s = 0.f;
#pragma unroll
            for (int ni = 0; ni < 4; ++ni)
                s += fast_tanh(qv[ni] + acc[mi][ni][jj]) * vv[ni];
            s += __shfl_xor(s, 1);
            s += __shfl_xor(s, 2);
            s += __shfl_xor(s, 4);
            s += __shfl_xor(s, 8);
            if (lane15 == 0)
                ps[(wr * 64 + mi * 16 + h * 4 + jj) * 2 + wc] = s;
        }
    __syncthreads();
    if (tid < 128)
        scores_p[(size_t)n * (NB * NS) + row0 + tid] = ps[tid * 2] + ps[tid * 2 + 1];
}

// ---------------- fallback (R4): f32 A reg-staged ----------------
__global__ __launch_bounds__(256, 4) void score_kernel_f32(
    const float* __restrict__ E, const __bf16* __restrict__ We,
    const float* __restrict__ qp, const float* __restrict__ Vv,
    float* __restrict__ scores_p) {
    __shared__ __align__(16) __bf16 As[2][128 * 32];
    __shared__ __align__(16) __bf16 Bs[2][128 * 32];
    __shared__ float ps_lds[128][2];

    const int tid    = threadIdx.x;
    const int lane   = tid & 63;
    const int lane15 = lane & 15;
    const int h      = lane >> 4;
    const int wid    = tid >> 6;
    const int wr     = wid >> 1;
    const int wc     = wid & 1;

    const int bid = blockIdx.x;
    const int xcd = bid & 7;
    const int j   = bid >> 3;
    const int m   = xcd * 64 + (j >> 3);
    const int n   = j & 7;
    const int row0  = m * 128;
    const int ncol0 = n * 128;
    const int b     = m >> 4;

    f32x4 acc[4][4];
#pragma unroll
    for (int mi = 0; mi < 4; ++mi)
#pragma unroll
        for (int ni = 0; ni < 4; ++ni)
            acc[mi][ni] = (f32x4){0.f, 0.f, 0.f, 0.f};

    const int wbyte = wid * 1024;
    float4 st[4];

#define A_LOAD(kc)                                                                     \
    {                                                                                  \
        _Pragma("unroll")                                                              \
        for (int i = 0; i < 4; ++i)                                                    \
            st[i] = *reinterpret_cast<const float4*>(                                  \
                E + (size_t)(row0 + i * 32 + (tid >> 3)) * NDE + (kc) + (tid & 7) * 4);\
    }

#define A_WRITE(buf)                                                                   \
    {                                                                                  \
        _Pragma("unroll")                                                              \
        for (int i = 0; i < 4; ++i) {                                                  \
            int r  = i * 32 + (tid >> 3);                                              \
            int sl = ((tid & 7) >> 1) ^ ((r >> 1) & 3);                                \
            union { __bf16 hh[4]; uint2 u; } pk;                                       \
            pk.hh[0] = (__bf16)st[i].x; pk.hh[1] = (__bf16)st[i].y;                    \
            pk.hh[2] = (__bf16)st[i].z; pk.hh[3] = (__bf16)st[i].w;                    \
            *reinterpret_cast<uint2*>((char*)&As[buf][0] + r * 64 + sl * 16 + (tid & 1) * 8) = pk.u; \
        }                                                                              \
    }

#define B_STAGE(buf, kc)                                                               \
    {                                                                                  \
        _Pragma("unroll")                                                              \
        for (int i = 0; i < 2; ++i) {                                                  \
            int ib = i * 4096 + tid * 16;                                              \
            int r  = ib >> 6;                                                          \
            int sl = (ib >> 4) & 3;                                                    \
            int sg = sl ^ ((r >> 1) & 3);                                              \
            const __bf16* g = We + (size_t)(ncol0 + r) * NDE + (kc) + sg * 8;          \
            __builtin_amdgcn_global_load_lds(                                          \
                (const __attribute__((address_space(1))) unsigned*)g,                  \
                (__attribute__((address_space(3))) unsigned*)((char*)&Bs[buf][0] + i * 4096 + wbyte), \
                16, 0, 0);                                                             \
        }                                                                              \
    }

    A_LOAD(0)
    B_STAGE(0, 0)
    A_WRITE(0)
    __syncthreads();

    for (int it = 0; it < 32; ++it) {
        const int cur = it & 1;
        if (it < 31) {
            A_LOAD((it + 1) * 32)
            B_STAGE(cur ^ 1, (it + 1) * 32)
        }
        const char* Ab = (const char*)&As[cur][0];
        const char* Bb = (const char*)&Bs[cur][0];
        bf16x8 bfr[4], afr[4];
#pragma unroll
        for (int ni = 0; ni < 4; ++ni) {
            int cr = wc * 64 + ni * 16 + lane15;
            bfr[ni] = *reinterpret_cast<const bf16x8*>(Bb + cr * 64 + ((h ^ ((cr >> 1) & 3)) * 16));
        }
#pragma unroll
        for (int mi = 0; mi < 4; ++mi) {
            int r = wr * 64 + mi * 16 + lane15;
            afr[mi] = *reinterpret_cast<const bf16x8*>(Ab + r * 64 + ((h ^ ((r >> 1) & 3)) * 16));
        }
#pragma unroll
        for (int mi = 0; mi < 4; ++mi)
#pragma unroll
            for (int ni = 0; ni < 4; ++ni)
                acc[mi][ni] = __builtin_amdgcn_mfma_f32_16x16x32_bf16(afr[mi], bfr[ni], acc[mi][ni], 0, 0, 0);
        if (it < 31) A_WRITE(cur ^ 1)
        __syncthreads();
    }

    float qv[4], vv[4];
#pragma unroll
    for (int ni = 0; ni < 4; ++ni) {
        int col = ncol0 + wc * 64 + ni * 16 + lane15;
        qv[ni] = qp[(size_t)b * NDA + col];
        vv[ni] = Vv[col];
    }
#pragma unroll
    for (int mi = 0; mi < 4; ++mi)
#pragma unroll
        for (int jj = 0; jj < 4; ++jj) {
            float s = 0.f;
#pragma unroll
            for (int ni = 0; ni < 4; ++ni)
                s += fast_tanh(qv[ni] + acc[mi][ni][jj]) * vv[ni];
            s += __shfl_xor(s, 1);
            s += __shfl_xor(s, 2);
            s += __shfl_xor(s, 4);
            s += __shfl_xor(s, 8);
            if (lane15 == 0)
                ps_lds[wr * 64 + mi * 16 + h * 4 + jj][wc] = s;
        }
    __syncthreads();
    if (tid < 128)
        scores_p[(size_t)n * (NB * NS) + row0 + tid] = ps_lds[tid][0] + ps_lds[tid][1];
}

// ---------------- masked softmax over s (sums 8 partials), per b ----------------
__global__ void softmax_kernel(const float* __restrict__ sp, const int* __restrict__ mask,
                               float* __restrict__ wout) {
    int b = blockIdx.x;
    const int* mrow = mask + (size_t)b * NS;
    float v[8];
    float lmax = -INFINITY;
#pragma unroll
    for (int jj = 0; jj < 8; ++jj) {
        int s = threadIdx.x + 256 * jj;
        float sc = 0.f;
#pragma unroll
        for (int nn = 0; nn < 8; ++nn) sc += sp[(size_t)nn * (NB * NS) + b * NS + s];
        v[jj] = (mrow[s] == 0) ? NEGV : sc;
        lmax = fmaxf(lmax, v[jj]);
    }
#pragma unroll
    for (int mm = 1; mm <= 32; mm <<= 1) lmax = fmaxf(lmax, __shfl_xor(lmax, mm));
    __shared__ float redm[4], reds[4];
    if ((threadIdx.x & 63) == 0) redm[threadIdx.x >> 6] = lmax;
    __syncthreads();
    float bmax = fmaxf(fmaxf(redm[0], redm[1]), fmaxf(redm[2], redm[3]));
    float lsum = 0.f;
#pragma unroll
    for (int jj = 0; jj < 8; ++jj) { v[jj] = __expf(v[jj] - bmax); lsum += v[jj]; }
#pragma unroll
    for (int mm = 1; mm <= 32; mm <<= 1) lsum += __shfl_xor(lsum, mm);
    if ((threadIdx.x & 63) == 0) reds[threadIdx.x >> 6] = lsum;
    __syncthreads();
    float inv = __fdividef(1.0f, reds[0] + reds[1] + reds[2] + reds[3]);
#pragma unroll
    for (int jj = 0; jj < 8; ++jj) wout[(size_t)b * NS + threadIdx.x + 256 * jj] = v[jj] * inv;
}

// ---------------- context = w @ Eb (bf16 E copy, L3-resident) ----------------
// grid 256: b = bx>>3, d-chunk (128 d) = bx&7. 256 thr: 32 d-groups(4 bf16) x 8 s-splits(256).
__global__ void context_bf16(const __bf16* __restrict__ Eb, const float* __restrict__ w,
                             float* __restrict__ ctx) {
    int b  = blockIdx.x >> 3;
    int dc = blockIdx.x & 7;
    int dg = threadIdx.x & 31;
    int ss = threadIdx.x >> 5;
    const __bf16* base = Eb + (size_t)b * NS * NDE + (size_t)(ss * 256) * NDE + dc * 128 + dg * 4;
    const float* wb = w + (size_t)b * NS + ss * 256;
    float a0 = 0.f, a1 = 0.f, a2 = 0.f, a3 = 0.f;
#pragma unroll 8
    for (int s = 0; s < 256; ++s) {
        float ws = wb[s];
        uint2 u = *reinterpret_cast<const uint2*>(base + (size_t)s * NDE);
        a0 = fmaf(ws, bfu2f((unsigned short)(u.x & 0xffff)), a0);
        a1 = fmaf(ws, bfu2f((unsigned short)(u.x >> 16)), a1);
        a2 = fmaf(ws, bfu2f((unsigned short)(u.y & 0xffff)), a2);
        a3 = fmaf(ws, bfu2f((unsigned short)(u.y >> 16)), a3);
    }
    __shared__ float4 part[256];
    part[threadIdx.x] = make_float4(a0, a1, a2, a3);
    __syncthreads();
    if (threadIdx.x < 32) {
        float4 r = part[threadIdx.x];
#pragma unroll
        for (int k = 1; k < 8; ++k) {
            float4 p = part[threadIdx.x + 32 * k];
            r.x += p.x; r.y += p.y; r.z += p.z; r.w += p.w;
        }
        *reinterpret_cast<float4*>(ctx + (size_t)b * NDD + dc * 128 + threadIdx.x * 4) = r;
    }
}

// ---------------- fallback context: f32 E ----------------
__global__ void context_kernel(const float* __restrict__ E, const float* __restrict__ w,
                               float* __restrict__ ctx) {
    int b  = blockIdx.x >> 3;
    int dc = blockIdx.x & 7;
    int d2 = dc * 64 + (threadIdx.x & 63);
    int s0 = (threadIdx.x >> 6) * 512;
    const float2* Eb = reinterpret_cast<const float2*>(E) + (size_t)b * NS * (NDE / 2);
    const float* wb = w + (size_t)b * NS;
    float ax = 0.f, ay = 0.f;
#pragma unroll 8
    for (int s = s0; s < s0 + 512; ++s) {
        float ws = wb[s];
        float2 e = Eb[(size_t)s * (NDE / 2) + d2];
        ax = fmaf(ws, e.x, ax);
        ay = fmaf(ws, e.y, ay);
    }
    __shared__ float2 part[256];
    part[threadIdx.x] = make_float2(ax, ay);
    __syncthreads();
    if (threadIdx.x < 64) {
        float2 p0 = part[threadIdx.x], p1 = part[threadIdx.x + 64];
        float2 p2 = part[threadIdx.x + 128], p3 = part[threadIdx.x + 192];
        float2 r = make_float2(p0.x + p1.x + p2.x + p3.x, p0.y + p1.y + p2.y + p3.y);
        reinterpret_cast<float2*>(ctx + (size_t)b * NDD + dc * 128)[threadIdx.x] = r;
    }
}

extern "C" void kernel_launch(void* const* d_in, const int* in_sizes, int n_in,
                              void* d_out, int out_size, void* d_ws, size_t ws_size,
                              hipStream_t stream) {
    const float* query = (const float*)d_in[0];
    const float* enc   = (const float*)d_in[1];
    const int*   mask  = (const int*)d_in[2];
    const float* Wc    = (const float*)d_in[3];
    const float* V     = (const float*)d_in[4];

    float* out = (float*)d_out;
    float* ctx = out;                       // (32,1024)
    float* wts = out + NB * NDD;            // (32,2048)

    const size_t WE_B = (size_t)NDA * NDE * 2;        // 2 MB
    const size_t QP_B = (size_t)NB * NDA * 4;         // 128 KB
    const size_t SP_B = (size_t)8 * NB * NS * 4;      // 2 MB
    const size_t EB_B = (size_t)NB * NS * NDE * 2;    // 134.2 MB

    char* ws = (char*)d_ws;
    __bf16* We = (__bf16*)ws;
    float*  qp = (float*)(ws + WE_B);
    float*  sp = (float*)(ws + WE_B + QP_B);
    __bf16* Eb = (__bf16*)(ws + WE_B + QP_B + SP_B);

    hipLaunchKernelGGL(prep_we,      dim3(1024),  dim3(256), 0, stream, Wc, We);
    hipLaunchKernelGGL(qproj_kernel, dim3(4, NB), dim3(256), 0, stream, query, Wc, qp);

    if (ws_size >= WE_B + QP_B + SP_B + EB_B) {
        hipLaunchKernelGGL(prep_e,           dim3(32768), dim3(256), 0, stream, enc, Eb);
        hipLaunchKernelGGL(score_kernel_bf16,dim3(4096),  dim3(256), 0, stream, Eb, We, qp, V, sp);
        hipLaunchKernelGGL(softmax_kernel,   dim3(NB),    dim3(256), 0, stream, sp, mask, wts);
        hipLaunchKernelGGL(context_bf16,     dim3(256),   dim3(256), 0, stream, Eb, wts, ctx);
    } else {
        hipLaunchKernelGGL(score_kernel_f32, dim3(4096),  dim3(256), 0, stream, enc, We, qp, V, sp);
        hipLaunchKernelGGL(softmax_kernel,   dim3(NB),    dim3(256), 0, stream, sp, mask, wts);
        hipLaunchKernelGGL(context_kernel,   dim3(256),   dim3(256), 0, stream, enc, wts, ctx);
    }
}

// Round 8
// 297.961 us; speedup vs baseline: 1.3115x; 1.0603x over previous
//
#include <hip/hip_runtime.h>
#include <hip/hip_bf16.h>

#define NB 32
#define NS 2048
#define NDD 1024
#define NDE 1024
#define NDA 1024
#define NEGV (-1000000000.0f)

typedef __attribute__((ext_vector_type(8))) __bf16 bf16x8;
typedef __attribute__((ext_vector_type(4))) float f32x4;

__device__ __forceinline__ float fast_tanh(float x) {
    x = fminf(10.0f, fmaxf(-10.0f, x));
    float e = __expf(2.0f * x);
    return __fdividef(e - 1.0f, e + 1.0f);
}

__device__ __forceinline__ float bfu2f(unsigned short v) {
    union { unsigned u; float f; } c; c.u = (unsigned)v << 16; return c.f;
}

#define BAR()  { asm volatile("" ::: "memory"); __builtin_amdgcn_s_barrier(); asm volatile("" ::: "memory"); }
#define BARV() { asm volatile("s_waitcnt vmcnt(0)" ::: "memory"); __builtin_amdgcn_s_barrier(); asm volatile("" ::: "memory"); }

// ---------------- We (f32) -> bf16 ----------------
__global__ void prep_we(const float* __restrict__ Wc, __bf16* __restrict__ We) {
    int f = blockIdx.x * 256 + threadIdx.x;
    int a  = f >> 8;
    int k4 = f & 255;
    float4 v = *reinterpret_cast<const float4*>(Wc + (size_t)a * (NDD + NDE) + NDD + k4 * 4);
    union { __bf16 h[4]; uint2 u; } pk;
    pk.h[0] = (__bf16)v.x; pk.h[1] = (__bf16)v.y;
    pk.h[2] = (__bf16)v.z; pk.h[3] = (__bf16)v.w;
    *reinterpret_cast<uint2*>(We + (size_t)a * NDE + k4 * 4) = pk.u;
}

// ---------------- E (f32) -> bf16, nontemporal f32 reads ----------------
__global__ void prep_e(const float* __restrict__ E, __bf16* __restrict__ Eb) {
    size_t i = ((size_t)blockIdx.x * 256 + threadIdx.x) * 8;
    f32x4 x = __builtin_nontemporal_load(reinterpret_cast<const f32x4*>(E + i));
    f32x4 y = __builtin_nontemporal_load(reinterpret_cast<const f32x4*>(E + i + 4));
    union { __bf16 h[8]; uint4 u; } pk;
    pk.h[0] = (__bf16)x[0]; pk.h[1] = (__bf16)x[1]; pk.h[2] = (__bf16)x[2]; pk.h[3] = (__bf16)x[3];
    pk.h[4] = (__bf16)y[0]; pk.h[5] = (__bf16)y[1]; pk.h[6] = (__bf16)y[2]; pk.h[7] = (__bf16)y[3];
    *reinterpret_cast<uint4*>(Eb + i) = pk.u;
}

// ---------------- q_proj = query @ Wq^T (f32, exact) ----------------
__global__ void qproj_kernel(const float* __restrict__ q, const float* __restrict__ Wc,
                             float* __restrict__ qp) {
    __shared__ float qs[NDD];
    int b = blockIdx.y;
    int a = blockIdx.x * 256 + threadIdx.x;
    float4 qv = *reinterpret_cast<const float4*>(q + (size_t)b * NDD + threadIdx.x * 4);
    *reinterpret_cast<float4*>(qs + threadIdx.x * 4) = qv;
    __syncthreads();
    const float* wrow = Wc + (size_t)a * (NDD + NDE);
    float acc = 0.f;
#pragma unroll 4
    for (int k4 = 0; k4 < 256; ++k4) {
        float4 w = *reinterpret_cast<const float4*>(wrow + k4 * 4);
        acc += qs[k4*4+0] * w.x + qs[k4*4+1] * w.y + qs[k4*4+2] * w.z + qs[k4*4+3] * w.w;
    }
    qp[(size_t)b * NDA + a] = acc;
}

// ---------------- 256x256 / BK=64 / 8-wave deep-pipelined score GEMM ----------------
// 512 thr = 8 waves (2M x 4N); per-wave C = 128x64 (8 m-frags x 4 n-frags).
// LDS 128 KB: A[2][256][64] + B[2][256][64] bf16, 8-slot involution swizzle slot^=(r&7).
// Per K-tile: all 8 next-tile global_load_lds issue at phase 0; 4 MFMA phases with
// barriers + setprio; single vmcnt(0) at tile end (loads ~2500 cyc old -> no stall).
__global__ __launch_bounds__(512, 2) void score256(
    const __bf16* __restrict__ Eb, const __bf16* __restrict__ We,
    const float* __restrict__ qp, const float* __restrict__ Vv,
    float* __restrict__ sp) {
    __shared__ __align__(16) __bf16 As[2][256 * 64];   // 32 KB each
    __shared__ __align__(16) __bf16 Bs[2][256 * 64];

    const int tid  = threadIdx.x;
    const int lane = tid & 63;
    const int l15  = lane & 15;
    const int h    = lane >> 4;          // 0..3
    const int wid  = tid >> 6;           // 0..7
    const int wr   = wid >> 2;           // 0..1 (row half, 128 rows)
    const int wc   = wid & 3;            // 0..3 (col quarter, 64 cols)

    const int bid = blockIdx.x;
    const int xcd = bid & 7;
    const int j   = bid >> 3;            // 0..127
    const int m   = xcd * 32 + (j >> 2); // 0..255
    const int n   = j & 3;               // 0..3
    const int row0  = m * 256;
    const int ncol0 = n * 256;
    const int b     = m >> 3;

    f32x4 acc[8][4];
#pragma unroll
    for (int mf = 0; mf < 8; ++mf)
#pragma unroll
        for (int nf = 0; nf < 4; ++nf)
            acc[mf][nf] = (f32x4){0.f, 0.f, 0.f, 0.f};

    // staging source offsets (pre-inverse-swizzled), elements
    int offE[4], offW[4];
#pragma unroll
    for (int i = 0; i < 4; ++i) {
        int rr = i * 64 + (tid >> 3);
        int sg = (tid & 7) ^ (rr & 7);
        offE[i] = (row0  + rr) * 1024 + sg * 8;
        offW[i] = (ncol0 + rr) * 1024 + sg * 8;
    }

    // frag read byte offsets (ks=0); ks=1 = ^64
    const int slot0 = ((h ^ (l15 & 7)) * 16);
    const int aoffl = (wr * 128 + l15) * 128 + slot0;
    const int boffl = (wc * 64  + l15) * 128 + slot0;

    // prologue: stage tile 0
#pragma unroll
    for (int i = 0; i < 4; ++i)
        __builtin_amdgcn_global_load_lds(
            (const __attribute__((address_space(1))) unsigned*)(Eb + offE[i]),
            (__attribute__((address_space(3))) unsigned*)((char*)&As[0][0] + i * 8192 + wid * 1024),
            16, 0, 0);
#pragma unroll
    for (int i = 0; i < 4; ++i)
        __builtin_amdgcn_global_load_lds(
            (const __attribute__((address_space(1))) unsigned*)(We + offW[i]),
            (__attribute__((address_space(3))) unsigned*)((char*)&Bs[0][0] + i * 8192 + wid * 1024),
            16, 0, 0);
    BARV();

#pragma unroll 2
    for (int T = 0; T < 16; ++T) {
        const int cur = T & 1;
        const char* Ab = (const char*)&As[cur][0];
        const char* Bb = (const char*)&Bs[cur][0];
        if (T < 15) {
            const int kcn = (T + 1) * 64;
            const int nxt = cur ^ 1;
#pragma unroll
            for (int i = 0; i < 4; ++i)
                __builtin_amdgcn_global_load_lds(
                    (const __attribute__((address_space(1))) unsigned*)(Eb + offE[i] + kcn),
                    (__attribute__((address_space(3))) unsigned*)((char*)&As[nxt][0] + i * 8192 + wid * 1024),
                    16, 0, 0);
#pragma unroll
            for (int i = 0; i < 4; ++i)
                __builtin_amdgcn_global_load_lds(
                    (const __attribute__((address_space(1))) unsigned*)(We + offW[i] + kcn),
                    (__attribute__((address_space(3))) unsigned*)((char*)&Bs[nxt][0] + i * 8192 + wid * 1024),
                    16, 0, 0);
        }
        bf16x8 afr[4][2], bfr[2][2][2];
        // ---- phase 0: quadrant (mh0, nh0): load A mh0 (8) + B nh0 (4)
#pragma unroll
        for (int mi = 0; mi < 4; ++mi) {
            afr[mi][0] = *reinterpret_cast<const bf16x8*>(Ab + (aoffl + mi * 2048));
            afr[mi][1] = *reinterpret_cast<const bf16x8*>(Ab + ((aoffl + mi * 2048) ^ 64));
        }
#pragma unroll
        for (int ni = 0; ni < 2; ++ni) {
            bfr[0][ni][0] = *reinterpret_cast<const bf16x8*>(Bb + (boffl + ni * 2048));
            bfr[0][ni][1] = *reinterpret_cast<const bf16x8*>(Bb + ((boffl + ni * 2048) ^ 64));
        }
        __builtin_amdgcn_s_setprio(1);
#pragma unroll
        for (int ks = 0; ks < 2; ++ks)
#pragma unroll
            for (int mi = 0; mi < 4; ++mi)
#pragma unroll
                for (int ni = 0; ni < 2; ++ni)
                    acc[mi][ni] = __builtin_amdgcn_mfma_f32_16x16x32_bf16(afr[mi][ks], bfr[0][ni][ks], acc[mi][ni], 0, 0, 0);
        __builtin_amdgcn_s_setprio(0);
        BAR();
        // ---- phase 1: (mh0, nh1): load B nh1 (4)
#pragma unroll
        for (int ni = 0; ni < 2; ++ni) {
            bfr[1][ni][0] = *reinterpret_cast<const bf16x8*>(Bb + (boffl + (2 + ni) * 2048));
            bfr[1][ni][1] = *reinterpret_cast<const bf16x8*>(Bb + ((boffl + (2 + ni) * 2048) ^ 64));
        }
        __builtin_amdgcn_s_setprio(1);
#pragma unroll
        for (int ks = 0; ks < 2; ++ks)
#pragma unroll
            for (int mi = 0; mi < 4; ++mi)
#pragma unroll
                for (int ni = 0; ni < 2; ++ni)
                    acc[mi][2 + ni] = __builtin_amdgcn_mfma_f32_16x16x32_bf16(afr[mi][ks], bfr[1][ni][ks], acc[mi][2 + ni], 0, 0, 0);
        __builtin_amdgcn_s_setprio(0);
        BAR();
        // ---- phase 2: (mh1, nh1): reload A mh1 (8)
#pragma unroll
        for (int mi = 0; mi < 4; ++mi) {
            afr[mi][0] = *reinterpret_cast<const bf16x8*>(Ab + (aoffl + (4 + mi) * 2048));
            afr[mi][1] = *reinterpret_cast<const bf16x8*>(Ab + ((aoffl + (4 + mi) * 2048) ^ 64));
        }
        __builtin_amdgcn_s_setprio(1);
#pragma unroll
        for (int ks = 0; ks < 2; ++ks)
#pragma unroll
            for (int mi = 0; mi < 4; ++mi)
#pragma unroll
                for (int ni = 0; ni < 2; ++ni)
                    acc[4 + mi][2 + ni] = __builtin_amdgcn_mfma_f32_16x16x32_bf16(afr[mi][ks], bfr[1][ni][ks], acc[4 + mi][2 + ni], 0, 0, 0);
        __builtin_amdgcn_s_setprio(0);
        BAR();
        // ---- phase 3: (mh1, nh0): no loads
        __builtin_amdgcn_s_setprio(1);
#pragma unroll
        for (int ks = 0; ks < 2; ++ks)
#pragma unroll
            for (int mi = 0; mi < 4; ++mi)
#pragma unroll
                for (int ni = 0; ni < 2; ++ni)
                    acc[4 + mi][ni] = __builtin_amdgcn_mfma_f32_16x16x32_bf16(afr[mi][ks], bfr[0][ni][ks], acc[4 + mi][ni], 0, 0, 0);
        __builtin_amdgcn_s_setprio(0);
        BARV();
    }

    // ---- epilogue: tanh(qp + e_proj) * V, reduce over cols ----
    float qv[4], vv[4];
#pragma unroll
    for (int nf = 0; nf < 4; ++nf) {
        int col = ncol0 + wc * 64 + nf * 16 + l15;
        qv[nf] = qp[(size_t)b * NDA + col];
        vv[nf] = Vv[col];
    }
    float* ps2 = reinterpret_cast<float*>(&As[0][0]);  // retired; [256][4] f32
#pragma unroll
    for (int mf = 0; mf < 8; ++mf)
#pragma unroll
        for (int jj = 0; jj < 4; ++jj) {
            float s = 0.f;
#pragma unroll
            for (int nf = 0; nf < 4; ++nf)
                s += fast_tanh(qv[nf] + acc[mf][nf][jj]) * vv[nf];
            s += __shfl_xor(s, 1);
            s += __shfl_xor(s, 2);
            s += __shfl_xor(s, 4);
            s += __shfl_xor(s, 8);
            if (l15 == 0)
                ps2[(wr * 128 + mf * 16 + h * 4 + jj) * 4 + wc] = s;
        }
    __syncthreads();
    if (tid < 256)
        sp[(size_t)n * (NB * NS) + row0 + tid] =
            ps2[tid * 4] + ps2[tid * 4 + 1] + ps2[tid * 4 + 2] + ps2[tid * 4 + 3];
}

// ---------------- fallback (R7): 128^2 bf16 score ----------------
__global__ __launch_bounds__(256) void score_kernel_bf16(
    const __bf16* __restrict__ Eb, const __bf16* __restrict__ We,
    const float* __restrict__ qp, const float* __restrict__ Vv,
    float* __restrict__ scores_p) {
    __shared__ __align__(16) __bf16 As[2][128 * 32];
    __shared__ __align__(16) __bf16 Bs[2][128 * 32];

    const int tid    = threadIdx.x;
    const int lane   = tid & 63;
    const int lane15 = lane & 15;
    const int h      = lane >> 4;
    const int wid    = tid >> 6;
    const int wr     = wid >> 1;
    const int wc     = wid & 1;

    const int bid = blockIdx.x;
    const int xcd = bid & 7;
    const int j   = bid >> 3;
    const int m   = xcd * 64 + (j >> 3);
    const int n   = j & 7;
    const int row0  = m * 128;
    const int ncol0 = n * 128;
    const int b     = m >> 4;

    f32x4 acc[4][4];
#pragma unroll
    for (int mi = 0; mi < 4; ++mi)
#pragma unroll
        for (int ni = 0; ni < 4; ++ni)
            acc[mi][ni] = (f32x4){0.f, 0.f, 0.f, 0.f};

    const int wbyte = wid * 1024;

#define STG(SRC, base_row, LDSBUF, kc)                                                 \
    {                                                                                  \
        _Pragma("unroll")                                                              \
        for (int i = 0; i < 2; ++i) {                                                  \
            int ib = i * 4096 + tid * 16;                                              \
            int r  = ib >> 6;                                                          \
            int sl = (ib >> 4) & 3;                                                    \
            int sg = sl ^ ((r >> 1) & 3);                                              \
            const __bf16* g = SRC + (size_t)((base_row) + r) * 1024 + (kc) + sg * 8;   \
            __builtin_amdgcn_global_load_lds(                                          \
                (const __attribute__((address_space(1))) unsigned*)g,                  \
                (__attribute__((address_space(3))) unsigned*)((char*)LDSBUF + i * 4096 + wbyte), \
                16, 0, 0);                                                             \
        }                                                                              \
    }

    STG(Eb, row0, &As[0][0], 0)
    STG(We, ncol0, &Bs[0][0], 0)
    __syncthreads();

    for (int it = 0; it < 32; ++it) {
        const int cur = it & 1;
        if (it < 31) {
            STG(Eb, row0, &As[cur ^ 1][0], (it + 1) * 32)
            STG(We, ncol0, &Bs[cur ^ 1][0], (it + 1) * 32)
        }
        const char* Ab = (const char*)&As[cur][0];
        const char* Bb = (const char*)&Bs[cur][0];
        bf16x8 bfr[4], afr[4];
#pragma unroll
        for (int ni = 0; ni < 4; ++ni) {
            int cr = wc * 64 + ni * 16 + lane15;
            bfr[ni] = *reinterpret_cast<const bf16x8*>(Bb + cr * 64 + ((h ^ ((cr >> 1) & 3)) * 16));
        }
#pragma unroll
        for (int mi = 0; mi < 4; ++mi) {
            int r = wr * 64 + mi * 16 + lane15;
            afr[mi] = *reinterpret_cast<const bf16x8*>(Ab + r * 64 + ((h ^ ((r >> 1) & 3)) * 16));
        }
#pragma unroll
        for (int mi = 0; mi < 4; ++mi)
#pragma unroll
            for (int ni = 0; ni < 4; ++ni)
                acc[mi][ni] = __builtin_amdgcn_mfma_f32_16x16x32_bf16(afr[mi], bfr[ni], acc[mi][ni], 0, 0, 0);
        __syncthreads();
    }

    float qv[4], vv[4];
#pragma unroll
    for (int ni = 0; ni < 4; ++ni) {
        int col = ncol0 + wc * 64 + ni * 16 + lane15;
        qv[ni] = qp[(size_t)b * NDA + col];
        vv[ni] = Vv[col];
    }
    float* ps = reinterpret_cast<float*>(&As[0][0]);
#pragma unroll
    for (int mi = 0; mi < 4; ++mi)
#pragma unroll
        for (int jj = 0; jj < 4; ++jj) {
            float s = 0.f;
#pragma unroll
            for (int ni = 0; ni < 4; ++ni)
                s += fast_tanh(qv[ni] + acc[mi][ni][jj]) * vv[ni];
            s += __shfl_xor(s, 1);
            s += __shfl_xor(s, 2);
            s += __shfl_xor(s, 4);
            s += __shfl_xor(s, 8);
            if (lane15 == 0)
                ps[(wr * 64 + mi * 16 + h * 4 + jj) * 2 + wc] = s;
        }
    __syncthreads();
    if (tid < 128)
        scores_p[(size_t)n * (NB * NS) + row0 + tid] = ps[tid * 2] + ps[tid * 2 + 1];
}

// ---------------- masked softmax over s (sums np partials), per b ----------------
__global__ void softmax_kernel(const float* __restrict__ sp, const int* __restrict__ mask,
                               float* __restrict__ wout, int np) {
    int b = blockIdx.x;
    const int* mrow = mask + (size_t)b * NS;
    float v[8];
    float lmax = -INFINITY;
#pragma unroll
    for (int jj = 0; jj < 8; ++jj) {
        int s = threadIdx.x + 256 * jj;
        float sc = 0.f;
        for (int nn = 0; nn < np; ++nn) sc += sp[(size_t)nn * (NB * NS) + b * NS + s];
        v[jj] = (mrow[s] == 0) ? NEGV : sc;
        lmax = fmaxf(lmax, v[jj]);
    }
#pragma unroll
    for (int mm = 1; mm <= 32; mm <<= 1) lmax = fmaxf(lmax, __shfl_xor(lmax, mm));
    __shared__ float redm[4], reds[4];
    if ((threadIdx.x & 63) == 0) redm[threadIdx.x >> 6] = lmax;
    __syncthreads();
    float bmax = fmaxf(fmaxf(redm[0], redm[1]), fmaxf(redm[2], redm[3]));
    float lsum = 0.f;
#pragma unroll
    for (int jj = 0; jj < 8; ++jj) { v[jj] = __expf(v[jj] - bmax); lsum += v[jj]; }
#pragma unroll
    for (int mm = 1; mm <= 32; mm <<= 1) lsum += __shfl_xor(lsum, mm);
    if ((threadIdx.x & 63) == 0) reds[threadIdx.x >> 6] = lsum;
    __syncthreads();
    float inv = __fdividef(1.0f, reds[0] + reds[1] + reds[2] + reds[3]);
#pragma unroll
    for (int jj = 0; jj < 8; ++jj) wout[(size_t)b * NS + threadIdx.x + 256 * jj] = v[jj] * inv;
}

// ---------------- context = w @ Eb (bf16 E copy, L3-resident) ----------------
__global__ void context_bf16(const __bf16* __restrict__ Eb, const float* __restrict__ w,
                             float* __restrict__ ctx) {
    int b  = blockIdx.x >> 3;
    int dc = blockIdx.x & 7;
    int dg = threadIdx.x & 31;
    int ss = threadIdx.x >> 5;
    const __bf16* base = Eb + (size_t)b * NS * NDE + (size_t)(ss * 256) * NDE + dc * 128 + dg * 4;
    const float* wb = w + (size_t)b * NS + ss * 256;
    float a0 = 0.f, a1 = 0.f, a2 = 0.f, a3 = 0.f;
#pragma unroll 8
    for (int s = 0; s < 256; ++s) {
        float ws = wb[s];
        uint2 u = *reinterpret_cast<const uint2*>(base + (size_t)s * NDE);
        a0 = fmaf(ws, bfu2f((unsigned short)(u.x & 0xffff)), a0);
        a1 = fmaf(ws, bfu2f((unsigned short)(u.x >> 16)), a1);
        a2 = fmaf(ws, bfu2f((unsigned short)(u.y & 0xffff)), a2);
        a3 = fmaf(ws, bfu2f((unsigned short)(u.y >> 16)), a3);
    }
    __shared__ float4 part[256];
    part[threadIdx.x] = make_float4(a0, a1, a2, a3);
    __syncthreads();
    if (threadIdx.x < 32) {
        float4 r = part[threadIdx.x];
#pragma unroll
        for (int k = 1; k < 8; ++k) {
            float4 p = part[threadIdx.x + 32 * k];
            r.x += p.x; r.y += p.y; r.z += p.z; r.w += p.w;
        }
        *reinterpret_cast<float4*>(ctx + (size_t)b * NDD + dc * 128 + threadIdx.x * 4) = r;
    }
}

extern "C" void kernel_launch(void* const* d_in, const int* in_sizes, int n_in,
                              void* d_out, int out_size, void* d_ws, size_t ws_size,
                              hipStream_t stream) {
    const float* query = (const float*)d_in[0];
    const float* enc   = (const float*)d_in[1];
    const int*   mask  = (const int*)d_in[2];
    const float* Wc    = (const float*)d_in[3];
    const float* V     = (const float*)d_in[4];

    float* out = (float*)d_out;
    float* ctx = out;                       // (32,1024)
    float* wts = out + NB * NDD;            // (32,2048)

    const size_t WE_B = (size_t)NDA * NDE * 2;        // 2 MB
    const size_t QP_B = (size_t)NB * NDA * 4;         // 128 KB
    const size_t SP_B = (size_t)8 * NB * NS * 4;      // 2 MB
    const size_t EB_B = (size_t)NB * NS * NDE * 2;    // 134.2 MB

    char* ws = (char*)d_ws;
    __bf16* We = (__bf16*)ws;
    float*  qp = (float*)(ws + WE_B);
    float*  sp = (float*)(ws + WE_B + QP_B);
    __bf16* Eb = (__bf16*)(ws + WE_B + QP_B + SP_B);

    hipLaunchKernelGGL(prep_we,      dim3(1024),  dim3(256), 0, stream, Wc, We);
    hipLaunchKernelGGL(qproj_kernel, dim3(4, NB), dim3(256), 0, stream, query, Wc, qp);

    if (ws_size >= WE_B + QP_B + SP_B + EB_B) {
        hipLaunchKernelGGL(prep_e,         dim3(32768), dim3(256), 0, stream, enc, Eb);
        hipLaunchKernelGGL(score256,       dim3(1024),  dim3(512), 0, stream, Eb, We, qp, V, sp);
        hipLaunchKernelGGL(softmax_kernel, dim3(NB),    dim3(256), 0, stream, sp, mask, wts, 4);
        hipLaunchKernelGGL(context_bf16,   dim3(256),   dim3(256), 0, stream, Eb, wts, ctx);
    } else {
        // no-workspace fallback is not expected; reuse 128^2 kernel reading enc as bf16 is
        // impossible, so fall back to staging through whatever ws we have only if it fits.
        hipLaunchKernelGGL(prep_e,         dim3(32768), dim3(256), 0, stream, enc, Eb);
        hipLaunchKernelGGL(score_kernel_bf16, dim3(4096), dim3(256), 0, stream, Eb, We, qp, V, sp);
        hipLaunchKernelGGL(softmax_kernel, dim3(NB),    dim3(256), 0, stream, sp, mask, wts, 8);
        hipLaunchKernelGGL(context_bf16,   dim3(256),   dim3(256), 0, stream, Eb, wts, ctx);
    }
}

// Round 9
// 296.405 us; speedup vs baseline: 1.3183x; 1.0052x over previous
//
#include <hip/hip_runtime.h>
#include <hip/hip_bf16.h>

#define NB 32
#define NS 2048
#define NDD 1024
#define NDE 1024
#define NDA 1024
#define NEGV (-1000000000.0f)

typedef __attribute__((ext_vector_type(8))) __bf16 bf16x8;
typedef __attribute__((ext_vector_type(4))) float f32x4;

__device__ __forceinline__ float fast_tanh(float x) {
    x = fminf(10.0f, fmaxf(-10.0f, x));
    float e = __expf(2.0f * x);
    return __fdividef(e - 1.0f, e + 1.0f);
}

__device__ __forceinline__ float bfu2f(unsigned short v) {
    union { unsigned u; float f; } c; c.u = (unsigned)v << 16; return c.f;
}

// ---------------- We (f32) -> bf16 ----------------
__global__ void prep_we(const float* __restrict__ Wc, __bf16* __restrict__ We) {
    int f = blockIdx.x * 256 + threadIdx.x;
    int a  = f >> 8;
    int k4 = f & 255;
    float4 v = *reinterpret_cast<const float4*>(Wc + (size_t)a * (NDD + NDE) + NDD + k4 * 4);
    union { __bf16 h[4]; uint2 u; } pk;
    pk.h[0] = (__bf16)v.x; pk.h[1] = (__bf16)v.y;
    pk.h[2] = (__bf16)v.z; pk.h[3] = (__bf16)v.w;
    *reinterpret_cast<uint2*>(We + (size_t)a * NDE + k4 * 4) = pk.u;
}

// ---------------- E (f32) -> bf16, nontemporal f32 reads ----------------
__global__ void prep_e(const float* __restrict__ E, __bf16* __restrict__ Eb) {
    size_t i = ((size_t)blockIdx.x * 256 + threadIdx.x) * 8;
    f32x4 x = __builtin_nontemporal_load(reinterpret_cast<const f32x4*>(E + i));
    f32x4 y = __builtin_nontemporal_load(reinterpret_cast<const f32x4*>(E + i + 4));
    union { __bf16 h[8]; uint4 u; } pk;
    pk.h[0] = (__bf16)x[0]; pk.h[1] = (__bf16)x[1]; pk.h[2] = (__bf16)x[2]; pk.h[3] = (__bf16)x[3];
    pk.h[4] = (__bf16)y[0]; pk.h[5] = (__bf16)y[1]; pk.h[6] = (__bf16)y[2]; pk.h[7] = (__bf16)y[3];
    *reinterpret_cast<uint4*>(Eb + i) = pk.u;
}

// ---------------- q_proj = query @ Wq^T (f32, exact) ----------------
__global__ void qproj_kernel(const float* __restrict__ q, const float* __restrict__ Wc,
                             float* __restrict__ qp) {
    __shared__ float qs[NDD];
    int b = blockIdx.y;
    int a = blockIdx.x * 256 + threadIdx.x;
    float4 qv = *reinterpret_cast<const float4*>(q + (size_t)b * NDD + threadIdx.x * 4);
    *reinterpret_cast<float4*>(qs + threadIdx.x * 4) = qv;
    __syncthreads();
    const float* wrow = Wc + (size_t)a * (NDD + NDE);
    float acc = 0.f;
#pragma unroll 4
    for (int k4 = 0; k4 < 256; ++k4) {
        float4 w = *reinterpret_cast<const float4*>(wrow + k4 * 4);
        acc += qs[k4*4+0] * w.x + qs[k4*4+1] * w.y + qs[k4*4+2] * w.z + qs[k4*4+3] * w.w;
    }
    qp[(size_t)b * NDA + a] = acc;
}

// ---------------- 256x256 / BK=64 / 8-wave score GEMM, single-barrier m97 schedule ----------------
// 512 thr = 8 waves (2M x 4N); per-wave C = 128x64 (8 mf x 4 nf).
// LDS 128 KB: A[2][256][64] + B[2][256][64] bf16, 8-slot involution swizzle (slot ^= r&7).
// Per K-tile: issue 8 next-tile global_load_lds, 24 ds_read_b128 + 64 MFMA straight-line
// (compiler pipelines), ONE __syncthreads (compiler emits the vmcnt/lgkm drain).
__global__ __launch_bounds__(512, 2) void score256(
    const __bf16* __restrict__ Eb, const __bf16* __restrict__ We,
    const float* __restrict__ qp, const float* __restrict__ Vv,
    float* __restrict__ sp) {
    __shared__ __align__(16) __bf16 As[2][256 * 64];   // 32 KB each
    __shared__ __align__(16) __bf16 Bs[2][256 * 64];

    const int tid  = threadIdx.x;
    const int lane = tid & 63;
    const int l15  = lane & 15;
    const int h    = lane >> 4;          // 0..3
    const int wid  = tid >> 6;           // 0..7
    const int wr   = wid >> 2;           // 0..1 (row half, 128 rows)
    const int wc   = wid & 3;            // 0..3 (col quarter, 64 cols)

    const int bid = blockIdx.x;
    const int xcd = bid & 7;
    const int j   = bid >> 3;            // 0..127
    const int m   = xcd * 32 + (j >> 2); // 0..255
    const int n   = j & 3;               // 0..3
    const int row0  = m * 256;
    const int ncol0 = n * 256;
    const int b     = m >> 3;

    f32x4 acc[8][4];
#pragma unroll
    for (int mf = 0; mf < 8; ++mf)
#pragma unroll
        for (int nf = 0; nf < 4; ++nf)
            acc[mf][nf] = (f32x4){0.f, 0.f, 0.f, 0.f};

    // staging source offsets (pre-inverse-swizzled), elements
    int offE[4], offW[4];
#pragma unroll
    for (int i = 0; i < 4; ++i) {
        int rr = i * 64 + (tid >> 3);
        int sg = (tid & 7) ^ (rr & 7);
        offE[i] = (row0  + rr) * 1024 + sg * 8;
        offW[i] = (ncol0 + rr) * 1024 + sg * 8;
    }

    // frag read byte offsets (ks=0); ks=1 = ^64
    const int slot0 = ((h ^ (l15 & 7)) * 16);
    const int aoffl = (wr * 128 + l15) * 128 + slot0;
    const int boffl = (wc * 64  + l15) * 128 + slot0;

#define STAGE8(abuf, bbuf, kc)                                                          \
    {                                                                                   \
        _Pragma("unroll")                                                               \
        for (int i = 0; i < 4; ++i)                                                     \
            __builtin_amdgcn_global_load_lds(                                           \
                (const __attribute__((address_space(1))) unsigned*)(Eb + offE[i] + (kc)),\
                (__attribute__((address_space(3))) unsigned*)((char*)(abuf) + i * 8192 + wid * 1024), \
                16, 0, 0);                                                              \
        _Pragma("unroll")                                                               \
        for (int i = 0; i < 4; ++i)                                                     \
            __builtin_amdgcn_global_load_lds(                                           \
                (const __attribute__((address_space(1))) unsigned*)(We + offW[i] + (kc)),\
                (__attribute__((address_space(3))) unsigned*)((char*)(bbuf) + i * 8192 + wid * 1024), \
                16, 0, 0);                                                              \
    }

    // prologue: stage tile 0
    STAGE8(&As[0][0], &Bs[0][0], 0)
    __syncthreads();

    for (int T = 0; T < 16; ++T) {
        const int cur = T & 1;
        const char* Ab = (const char*)&As[cur][0];
        const char* Bb = (const char*)&Bs[cur][0];
        if (T < 15) STAGE8(&As[cur ^ 1][0], &Bs[cur ^ 1][0], (T + 1) * 64)

        bf16x8 bfr[4][2], afr[4][2];
#pragma unroll
        for (int nf = 0; nf < 4; ++nf) {
            bfr[nf][0] = *reinterpret_cast<const bf16x8*>(Bb + (boffl + nf * 2048));
            bfr[nf][1] = *reinterpret_cast<const bf16x8*>(Bb + ((boffl + nf * 2048) ^ 64));
        }
#pragma unroll
        for (int mi = 0; mi < 4; ++mi) {
            afr[mi][0] = *reinterpret_cast<const bf16x8*>(Ab + (aoffl + mi * 2048));
            afr[mi][1] = *reinterpret_cast<const bf16x8*>(Ab + ((aoffl + mi * 2048) ^ 64));
        }
        __builtin_amdgcn_s_setprio(1);
#pragma unroll
        for (int ks = 0; ks < 2; ++ks)
#pragma unroll
            for (int mi = 0; mi < 4; ++mi)
#pragma unroll
                for (int nf = 0; nf < 4; ++nf)
                    acc[mi][nf] = __builtin_amdgcn_mfma_f32_16x16x32_bf16(afr[mi][ks], bfr[nf][ks], acc[mi][nf], 0, 0, 0);
        __builtin_amdgcn_s_setprio(0);
#pragma unroll
        for (int mi = 0; mi < 4; ++mi) {
            afr[mi][0] = *reinterpret_cast<const bf16x8*>(Ab + (aoffl + (4 + mi) * 2048));
            afr[mi][1] = *reinterpret_cast<const bf16x8*>(Ab + ((aoffl + (4 + mi) * 2048) ^ 64));
        }
        __builtin_amdgcn_s_setprio(1);
#pragma unroll
        for (int ks = 0; ks < 2; ++ks)
#pragma unroll
            for (int mi = 0; mi < 4; ++mi)
#pragma unroll
                for (int nf = 0; nf < 4; ++nf)
                    acc[4 + mi][nf] = __builtin_amdgcn_mfma_f32_16x16x32_bf16(afr[mi][ks], bfr[nf][ks], acc[4 + mi][nf], 0, 0, 0);
        __builtin_amdgcn_s_setprio(0);
        __syncthreads();
    }

    // ---- epilogue: tanh(qp + e_proj) * V, reduce over cols ----
    float qv[4], vv[4];
#pragma unroll
    for (int nf = 0; nf < 4; ++nf) {
        int col = ncol0 + wc * 64 + nf * 16 + l15;
        qv[nf] = qp[(size_t)b * NDA + col];
        vv[nf] = Vv[col];
    }
    float* ps2 = reinterpret_cast<float*>(&As[0][0]);  // retired; [256][4] f32
#pragma unroll
    for (int mf = 0; mf < 8; ++mf)
#pragma unroll
        for (int jj = 0; jj < 4; ++jj) {
            float s = 0.f;
#pragma unroll
            for (int nf = 0; nf < 4; ++nf)
                s += fast_tanh(qv[nf] + acc[mf][nf][jj]) * vv[nf];
            s += __shfl_xor(s, 1);
            s += __shfl_xor(s, 2);
            s += __shfl_xor(s, 4);
            s += __shfl_xor(s, 8);
            if (l15 == 0)
                ps2[(wr * 128 + mf * 16 + h * 4 + jj) * 4 + wc] = s;
        }
    __syncthreads();
    if (tid < 256)
        sp[(size_t)n * (NB * NS) + row0 + tid] =
            ps2[tid * 4] + ps2[tid * 4 + 1] + ps2[tid * 4 + 2] + ps2[tid * 4 + 3];
}

// ---------------- masked softmax over s (sums np partials), per b ----------------
__global__ void softmax_kernel(const float* __restrict__ sp, const int* __restrict__ mask,
                               float* __restrict__ wout, int np) {
    int b = blockIdx.x;
    const int* mrow = mask + (size_t)b * NS;
    float v[8];
    float lmax = -INFINITY;
#pragma unroll
    for (int jj = 0; jj < 8; ++jj) {
        int s = threadIdx.x + 256 * jj;
        float sc = 0.f;
        for (int nn = 0; nn < np; ++nn) sc += sp[(size_t)nn * (NB * NS) + b * NS + s];
        v[jj] = (mrow[s] == 0) ? NEGV : sc;
        lmax = fmaxf(lmax, v[jj]);
    }
#pragma unroll
    for (int mm = 1; mm <= 32; mm <<= 1) lmax = fmaxf(lmax, __shfl_xor(lmax, mm));
    __shared__ float redm[4], reds[4];
    if ((threadIdx.x & 63) == 0) redm[threadIdx.x >> 6] = lmax;
    __syncthreads();
    float bmax = fmaxf(fmaxf(redm[0], redm[1]), fmaxf(redm[2], redm[3]));
    float lsum = 0.f;
#pragma unroll
    for (int jj = 0; jj < 8; ++jj) { v[jj] = __expf(v[jj] - bmax); lsum += v[jj]; }
#pragma unroll
    for (int mm = 1; mm <= 32; mm <<= 1) lsum += __shfl_xor(lsum, mm);
    if ((threadIdx.x & 63) == 0) reds[threadIdx.x >> 6] = lsum;
    __syncthreads();
    float inv = __fdividef(1.0f, reds[0] + reds[1] + reds[2] + reds[3]);
#pragma unroll
    for (int jj = 0; jj < 8; ++jj) wout[(size_t)b * NS + threadIdx.x + 256 * jj] = v[jj] * inv;
}

// ---------------- context = w @ Eb (bf16 E copy, L3-resident) ----------------
__global__ void context_bf16(const __bf16* __restrict__ Eb, const float* __restrict__ w,
                             float* __restrict__ ctx) {
    int b  = blockIdx.x >> 3;
    int dc = blockIdx.x & 7;
    int dg = threadIdx.x & 31;
    int ss = threadIdx.x >> 5;
    const __bf16* base = Eb + (size_t)b * NS * NDE + (size_t)(ss * 256) * NDE + dc * 128 + dg * 4;
    const float* wb = w + (size_t)b * NS + ss * 256;
    float a0 = 0.f, a1 = 0.f, a2 = 0.f, a3 = 0.f;
#pragma unroll 8
    for (int s = 0; s < 256; ++s) {
        float ws = wb[s];
        uint2 u = *reinterpret_cast<const uint2*>(base + (size_t)s * NDE);
        a0 = fmaf(ws, bfu2f((unsigned short)(u.x & 0xffff)), a0);
        a1 = fmaf(ws, bfu2f((unsigned short)(u.x >> 16)), a1);
        a2 = fmaf(ws, bfu2f((unsigned short)(u.y & 0xffff)), a2);
        a3 = fmaf(ws, bfu2f((unsigned short)(u.y >> 16)), a3);
    }
    __shared__ float4 part[256];
    part[threadIdx.x] = make_float4(a0, a1, a2, a3);
    __syncthreads();
    if (threadIdx.x < 32) {
        float4 r = part[threadIdx.x];
#pragma unroll
        for (int k = 1; k < 8; ++k) {
            float4 p = part[threadIdx.x + 32 * k];
            r.x += p.x; r.y += p.y; r.z += p.z; r.w += p.w;
        }
        *reinterpret_cast<float4*>(ctx + (size_t)b * NDD + dc * 128 + threadIdx.x * 4) = r;
    }
}

extern "C" void kernel_launch(void* const* d_in, const int* in_sizes, int n_in,
                              void* d_out, int out_size, void* d_ws, size_t ws_size,
                              hipStream_t stream) {
    const float* query = (const float*)d_in[0];
    const float* enc   = (const float*)d_in[1];
    const int*   mask  = (const int*)d_in[2];
    const float* Wc    = (const float*)d_in[3];
    const float* V     = (const float*)d_in[4];

    float* out = (float*)d_out;
    float* ctx = out;                       // (32,1024)
    float* wts = out + NB * NDD;            // (32,2048)

    const size_t WE_B = (size_t)NDA * NDE * 2;        // 2 MB
    const size_t QP_B = (size_t)NB * NDA * 4;         // 128 KB
    const size_t SP_B = (size_t)8 * NB * NS * 4;      // 2 MB
    char* ws = (char*)d_ws;
    __bf16* We = (__bf16*)ws;
    float*  qp = (float*)(ws + WE_B);
    float*  sp = (float*)(ws + WE_B + QP_B);
    __bf16* Eb = (__bf16*)(ws + WE_B + QP_B + SP_B);

    hipLaunchKernelGGL(prep_we,      dim3(1024),  dim3(256), 0, stream, Wc, We);
    hipLaunchKernelGGL(qproj_kernel, dim3(4, NB), dim3(256), 0, stream, query, Wc, qp);
    hipLaunchKernelGGL(prep_e,       dim3(32768), dim3(256), 0, stream, enc, Eb);
    hipLaunchKernelGGL(score256,     dim3(1024),  dim3(512), 0, stream, Eb, We, qp, V, sp);
    hipLaunchKernelGGL(softmax_kernel, dim3(NB),  dim3(256), 0, stream, sp, mask, wts, 4);
    hipLaunchKernelGGL(context_bf16, dim3(256),   dim3(256), 0, stream, Eb, wts, ctx);
}